// Round 9
// baseline (156.615 us; speedup 1.0000x reference)
//
#include <hip/hip_runtime.h>
#include <hip/hip_bf16.h>

#define TOKENS 2048
#define FDIM 512
#define HDIM 2048
#define NEXP 8
#define PI_F 3.14159265358979323846f

typedef __attribute__((ext_vector_type(8))) short bf16x8;
typedef __attribute__((ext_vector_type(4))) float f32x4;

__device__ __forceinline__ unsigned short f2bf(float f) {
  unsigned int u = __float_as_uint(f);
  unsigned int r = (u + 0x7fffu + ((u >> 16) & 1u)) >> 16;
  return (unsigned short)r;
}

__device__ __forceinline__ void gload16(const void* g, void* l) {
  __builtin_amdgcn_global_load_lds(
      (const __attribute__((address_space(1))) unsigned int*)g,
      (__attribute__((address_space(3))) unsigned int*)l, 16, 0, 0);
}

// ---------------- routing (8 tokens/block, width-32 reduce) ----------------
__global__ __launch_bounds__(256) void route_kernel(
    const float* __restrict__ xr, const float* __restrict__ xi,
    int* __restrict__ idx, int* __restrict__ counts)
{
  int tid = threadIdx.x;
  int t = blockIdx.x * 8 + (tid >> 5);
  int l = tid & 31;
  const float* r  = xr + (size_t)t * FDIM;
  const float* im = xi + (size_t)t * FDIM;
  float sc = 0.f, ss = 0.f;
  #pragma unroll
  for (int p = 0; p < 4; ++p) {
    int f = p * 128 + l * 4;
    float4 a4 = *(const float4*)(r + f);
    float4 b4 = *(const float4*)(im + f);
    float av[4] = {a4.x, a4.y, a4.z, a4.w};
    float bv[4] = {b4.x, b4.y, b4.z, b4.w};
    #pragma unroll
    for (int j = 0; j < 4; ++j) {
      float h2 = av[j] * av[j] + bv[j] * bv[j];
      if (h2 > 0.f) {
        float rs = rsqrtf(h2);
        sc += av[j] * rs;
        ss += bv[j] * rs;
      } else {
        sc += 1.f;   // atan2(0,0)=0 -> cos=1, sin=0
      }
    }
  }
  #pragma unroll
  for (int off = 16; off > 0; off >>= 1) {
    sc += __shfl_down(sc, off, 32);
    ss += __shfl_down(ss, off, 32);
  }
  if (l == 0) {
    float phase = atan2f(ss, sc);
    float norm = (phase + PI_F) / (2.f * PI_F);
    int e = (int)floorf(norm * (float)NEXP);
    e = min(max(e, 0), NEXP - 1);
    idx[t] = e;
    atomicAdd(&counts[e], 1);
  }
}

// deterministic scatter: perm within each expert in ascending token order
__global__ __launch_bounds__(256) void scatter_kernel(
    const int* __restrict__ idx, const int* __restrict__ counts,
    int* __restrict__ offs, int* __restrict__ perm, int* __restrict__ rexp)
{
  __shared__ int base_e[NEXP];
  __shared__ int tcnt[256][NEXP];
  int tid = threadIdx.x;
  if (tid == 0) {
    int acc = 0;
    for (int e = 0; e < NEXP; ++e) { base_e[e] = acc; offs[e] = acc; acc += counts[e]; }
  }
  int t0 = tid * 8;
  int eo[8];
  int loc[NEXP];
  #pragma unroll
  for (int e = 0; e < NEXP; ++e) loc[e] = 0;
  #pragma unroll
  for (int j = 0; j < 8; ++j) { eo[j] = idx[t0 + j]; loc[eo[j]]++; }
  #pragma unroll
  for (int e = 0; e < NEXP; ++e) tcnt[tid][e] = loc[e];
  __syncthreads();
  if (tid < NEXP) {
    int e = tid, run = 0;
    for (int i = 0; i < 256; ++i) { int v = tcnt[i][e]; tcnt[i][e] = run; run += v; }
  }
  __syncthreads();
  #pragma unroll
  for (int e = 0; e < NEXP; ++e) loc[e] = base_e[e] + tcnt[tid][e];
  #pragma unroll
  for (int j = 0; j < 8; ++j) {
    int e = eo[j];
    int pos = loc[e]++;
    perm[pos] = t0 + j;
    rexp[pos] = e;
  }
}

// ---------------- packing ----------------
__global__ __launch_bounds__(256) void pack_x_kernel(
    const float* __restrict__ xr, const float* __restrict__ xi,
    const int* __restrict__ perm,
    short* __restrict__ Ar, short* __restrict__ Ai)
{
  int gid = blockIdx.x * 256 + threadIdx.x;   // 2048 * 128
  int i = gid >> 7;
  int c4 = (gid & 127) * 4;
  int tok = perm[i];
  float4 r = *(const float4*)(xr + (size_t)tok * FDIM + c4);
  float4 m = *(const float4*)(xi + (size_t)tok * FDIM + c4);
  unsigned short orr[4] = { f2bf(r.x), f2bf(r.y), f2bf(r.z), f2bf(r.w) };
  unsigned short oii[4] = { f2bf(m.x), f2bf(m.y), f2bf(m.z), f2bf(m.w) };
  *(int2*)(Ar + (size_t)i * FDIM + c4) = *(const int2*)orr;
  *(int2*)(Ai + (size_t)i * FDIM + c4) = *(const int2*)oii;
}

// r5-proven: W[e][K][N] fp32 (r,i) -> Wp[e][2][N][K] bf16 (plane0=Wr^T, 1=Wi^T)
template<int K, int N>
__global__ __launch_bounds__(256) void pack_w_kernel(
    const float* __restrict__ Wr, const float* __restrict__ Wi,
    short* __restrict__ Wp)
{
  int e = blockIdx.z;
  int k0 = blockIdx.y * 32, n0 = blockIdx.x * 32;
  __shared__ float tr[32][33], ti[32][33];
  int tid = threadIdx.x;
  int row = tid >> 3, c4 = (tid & 7) * 4;
  const float* wr = Wr + ((size_t)e * K + k0) * N + n0;
  const float* wi = Wi + ((size_t)e * K + k0) * N + n0;
  float4 vr = *(const float4*)(wr + (size_t)row * N + c4);
  float4 vi = *(const float4*)(wi + (size_t)row * N + c4);
  *(float4*)&tr[row][c4] = vr;
  *(float4*)&ti[row][c4] = vi;
  __syncthreads();
  int nl = tid >> 3, k4 = (tid & 7) * 4;
  unsigned short pr[4], pi[4];
  #pragma unroll
  for (int j = 0; j < 4; ++j) {
    pr[j] = f2bf(tr[k4 + j][nl]);
    pi[j] = f2bf(ti[k4 + j][nl]);
  }
  size_t b0 = (((size_t)e * 2 + 0) * N + n0 + nl) * K + k0 + k4;
  size_t b1 = (((size_t)e * 2 + 1) * N + n0 + nl) * K + k0 + k4;
  *(int2*)(Wp + b0) = *(const int2*)pr;
  *(int2*)(Wp + b1) = *(const int2*)pi;
}

// ---------------- plane-separated complex MFMA grouped GEMM -----------------
// BM=128 x BNc=64, BK=32, 4 waves (2x2), wave-tile 64x32c (MF=4, NF=2).
// 3-deep pipeline: counted vmcnt(6) + raw s_barrier -- prefetch t+2 stays in
// flight across the barrier (never drain to 0 in-loop). 128 blocks/expert,
// expert -> XCD.
template<int LDK, int NC, int NX, bool IS_L1>
__global__ __launch_bounds__(256) void gemm_cplx(
    const short* __restrict__ Apr, const short* __restrict__ Api,
    const short* __restrict__ Wp,
    const int* __restrict__ counts, const int* __restrict__ offs,
    const float* __restrict__ bre, const float* __restrict__ bim,
    const float* __restrict__ mb,
    short* __restrict__ Or, short* __restrict__ Oi,
    unsigned int* __restrict__ P)
{
  constexpr int KT = 16;                     // 16 x BK=32 = 512 K-chunk
  int bid = blockIdx.x;
  int virt = (bid & 7) * 128 + (bid >> 3);   // expert e -> XCD e
  int e = virt >> 7, rem = virt & 127;
  int x = rem % NX;
  int q = rem / NX;
  int y = q & 3, s = q >> 2;                 // IS_L1: q<4 -> s=0
  int cnt = counts[e];
  int row0 = y * 128;
  if (row0 >= cnt) return;
  int base = offs[e];
  int n0c = x * 64;
  int kbase = s * 512;

  __shared__ __align__(16) short As[3][2][128][32];  // 48KB [buf][plane][row][k]
  __shared__ __align__(16) short Ws[3][2][64][32];   // 24KB

  int tid = threadIdx.x;
  int lane = tid & 63;
  int w = tid >> 6, wm = w >> 1, wn = w & 1;
  int lr = lane & 15, g = lane >> 4;
  int ssw = g ^ ((lr >> 1) & 3);             // swizzled 16B slot for reads

  int srl = tid >> 2, slt = tid & 3;
  int sc = (slt ^ ((srl >> 1) & 3)) * 16;    // pre-swizzled source byte offset
  const char* pA[2][2];
  #pragma unroll
  for (int rg = 0; rg < 2; ++rg) {
    int arow = min(row0 + rg * 64 + srl, cnt - 1);
    pA[rg][0] = (const char*)(Apr + (size_t)(base + arow) * LDK + kbase) + sc;
    pA[rg][1] = (const char*)(Api + (size_t)(base + arow) * LDK + kbase) + sc;
  }
  const short* We = Wp + (size_t)e * 2 * NC * LDK;
  const char* pW0 = (const char*)(We + (size_t)(n0c + srl) * LDK + kbase) + sc;
  const char* pW1 = (const char*)(We + ((size_t)NC + n0c + srl) * LDK + kbase) + sc;

  auto STAGE = [&](int buf, int t) {         // 6 gload16 per thread
    char* ab = (char*)&As[buf][0][0][0];
    gload16(pA[0][0] + t * 64, ab + tid * 16);
    gload16(pA[1][0] + t * 64, ab + 4096 + tid * 16);
    gload16(pA[0][1] + t * 64, ab + 8192 + tid * 16);
    gload16(pA[1][1] + t * 64, ab + 12288 + tid * 16);
    char* wb = (char*)&Ws[buf][0][0][0];
    gload16(pW0 + t * 64, wb + tid * 16);
    gload16(pW1 + t * 64, wb + 4096 + tid * 16);
  };

  f32x4 accr[4][2], acci[4][2];
  #pragma unroll
  for (int m = 0; m < 4; ++m)
    #pragma unroll
    for (int n = 0; n < 2; ++n) { accr[m][n] = 0.f; acci[m][n] = 0.f; }

  const bf16x8 SGN = {(short)0x8000, (short)0x8000, (short)0x8000, (short)0x8000,
                      (short)0x8000, (short)0x8000, (short)0x8000, (short)0x8000};

  auto COMPUTE = [&](int buf) {
    const short* Ab = &As[buf][0][0][0];
    const short* Wb = &Ws[buf][0][0][0];
    bf16x8 ar[4], ai[4], wr[2], wi[2], wni[2];
    #pragma unroll
    for (int m = 0; m < 4; ++m) {
      int off = (wm * 64 + m * 16 + lr) * 32 + ssw * 8;
      ar[m] = *(const bf16x8*)(Ab + off);
      ai[m] = *(const bf16x8*)(Ab + 4096 + off);
    }
    #pragma unroll
    for (int n = 0; n < 2; ++n) {
      int offw = (wn * 32 + n * 16 + lr) * 32 + ssw * 8;
      wr[n] = *(const bf16x8*)(Wb + offw);
      wi[n] = *(const bf16x8*)(Wb + 2048 + offw);
      wni[n] = wi[n] ^ SGN;
    }
    #pragma unroll
    for (int m = 0; m < 4; ++m)
      #pragma unroll
      for (int n = 0; n < 2; ++n) {
        accr[m][n] = __builtin_amdgcn_mfma_f32_16x16x32_bf16(ar[m], wr[n],  accr[m][n], 0, 0, 0);
        accr[m][n] = __builtin_amdgcn_mfma_f32_16x16x32_bf16(ai[m], wni[n], accr[m][n], 0, 0, 0);
        acci[m][n] = __builtin_amdgcn_mfma_f32_16x16x32_bf16(ar[m], wi[n],  acci[m][n], 0, 0, 0);
        acci[m][n] = __builtin_amdgcn_mfma_f32_16x16x32_bf16(ai[m], wr[n],  acci[m][n], 0, 0, 0);
      }
  };

  STAGE(0, 0);
  STAGE(1, 1);
  for (int t = 0; t < KT; ++t) {
    // wait for tile t's 6 loads only; tile t+1's 6 remain in flight (T4)
    if (t < KT - 1) asm volatile("s_waitcnt vmcnt(6)" ::: "memory");
    else            asm volatile("s_waitcnt vmcnt(0)" ::: "memory");
    __builtin_amdgcn_s_barrier();
    if (t + 2 < KT) STAGE((t + 2) % 3, t + 2);
    COMPUTE(t % 3);
  }

  // epilogue (no LDS use -> no trailing barrier needed)
  #pragma unroll
  for (int m = 0; m < 4; ++m) {
    #pragma unroll
    for (int qq = 0; qq < 4; ++qq) {
      int row = row0 + wm * 64 + m * 16 + g * 4 + qq;
      if (row >= cnt) continue;
      #pragma unroll
      for (int n = 0; n < 2; ++n) {
        int c = n0c + wn * 32 + n * 16 + lr;
        if constexpr (IS_L1) {
          float hr = accr[m][n][qq] + bre[e * NC + c];
          float hi = acci[m][n][qq] + bim[e * NC + c];
          float s2 = hr * hr + hi * hi + 1e-10f;
          float rr = __frsqrt_rn(s2);
          float amp = s2 * rr;
          float scl = fmaxf(amp + mb[e * NC + c], 0.f) * rr;
          Or[(size_t)(base + row) * NC + c] = (short)f2bf(hr * scl);
          Oi[(size_t)(base + row) * NC + c] = (short)f2bf(hi * scl);
        } else {
          // packed bf16 partial: lo16 = re, hi16 = im
          unsigned pv = (unsigned)f2bf(accr[m][n][qq])
                      | ((unsigned)f2bf(acci[m][n][qq]) << 16);
          P[((size_t)s * TOKENS + base + row) * 512 + c] = pv;
        }
      }
    }
  }
}

// ---------------- split-K finalize (bf16 packed partials) ----------------
__global__ __launch_bounds__(256) void finalize_kernel(
    const unsigned int* __restrict__ P, const float* __restrict__ br2,
    const float* __restrict__ bi2, const int* __restrict__ perm,
    const int* __restrict__ rexp, float* __restrict__ out)
{
  int gid = blockIdx.x * 256 + threadIdx.x;   // 2048 * 128
  int i = gid >> 7;
  int c4 = (gid & 127) * 4;
  float sr[4] = {0.f, 0.f, 0.f, 0.f}, si[4] = {0.f, 0.f, 0.f, 0.f};
  #pragma unroll
  for (int s = 0; s < 4; ++s) {
    uint4 u = *(const uint4*)(P + ((size_t)s * TOKENS + i) * 512 + c4);
    unsigned uv[4] = {u.x, u.y, u.z, u.w};
    #pragma unroll
    for (int j = 0; j < 4; ++j) {
      sr[j] += __uint_as_float(uv[j] << 16);
      si[j] += __uint_as_float(uv[j] & 0xFFFF0000u);
    }
  }
  int e = rexp[i], tok = perm[i];
  float4 br = *(const float4*)(br2 + e * FDIM + c4);
  float4 bi = *(const float4*)(bi2 + e * FDIM + c4);
  float4 vr = {sr[0] + br.x, sr[1] + br.y, sr[2] + br.z, sr[3] + br.w};
  float4 vi = {si[0] + bi.x, si[1] + bi.y, si[2] + bi.z, si[3] + bi.w};
  *(float4*)(out + (size_t)tok * FDIM + c4) = vr;
  *(float4*)(out + (size_t)TOKENS * FDIM + (size_t)tok * FDIM + c4) = vi;
}

extern "C" void kernel_launch(void* const* d_in, const int* in_sizes, int n_in,
                              void* d_out, int out_size, void* d_ws, size_t ws_size,
                              hipStream_t stream)
{
  const float* xr  = (const float*)d_in[0];
  const float* xi  = (const float*)d_in[1];
  const float* Wr1 = (const float*)d_in[2];
  const float* Wi1 = (const float*)d_in[3];
  const float* br1 = (const float*)d_in[4];
  const float* bi1 = (const float*)d_in[5];
  const float* mb  = (const float*)d_in[6];
  const float* Wr2 = (const float*)d_in[7];
  const float* Wi2 = (const float*)d_in[8];
  const float* br2 = (const float*)d_in[9];
  const float* bi2 = (const float*)d_in[10];
  float* out = (float*)d_out;

  char* ws = (char*)d_ws;
  int* counts = (int*)(ws + 0);
  int* offs   = (int*)(ws + 64);
  int* idx    = (int*)(ws + 128);
  int* perm   = (int*)(ws + 8320);
  int* rexp   = (int*)(ws + 16512);

  size_t off = 32768;
  short* A1r = (short*)(ws + off); off += (size_t)TOKENS * FDIM * 2;
  short* A1i = (short*)(ws + off); off += (size_t)TOKENS * FDIM * 2;
  short* A2r = (short*)(ws + off); off += (size_t)TOKENS * HDIM * 2;
  short* A2i = (short*)(ws + off); off += (size_t)TOKENS * HDIM * 2;
  short* W1p = (short*)(ws + off); off += (size_t)NEXP * 2 * HDIM * FDIM * 2;
  short* W2p = (short*)(ws + off); off += (size_t)NEXP * 2 * FDIM * HDIM * 2;
  unsigned int* P = (unsigned int*)(ws + off);   // 4 x 2048 x 512 uints = 16MB

  hipMemsetAsync(counts, 0, 64, stream);
  route_kernel<<<TOKENS / 8, 256, 0, stream>>>(xr, xi, idx, counts);
  scatter_kernel<<<1, 256, 0, stream>>>(idx, counts, offs, perm, rexp);

  pack_x_kernel<<<TOKENS * 128 / 256, 256, 0, stream>>>(xr, xi, perm, A1r, A1i);
  pack_w_kernel<FDIM, HDIM><<<dim3(HDIM / 32, FDIM / 32, NEXP), 256, 0, stream>>>(
      Wr1, Wi1, W1p);
  pack_w_kernel<HDIM, FDIM><<<dim3(FDIM / 32, HDIM / 32, NEXP), 256, 0, stream>>>(
      Wr2, Wi2, W2p);

  // layer1: K=512, NC=2048 (NX=32) -> A2 planes (bias+ModReLU fused)
  gemm_cplx<FDIM, HDIM, 32, true><<<1024, 256, 0, stream>>>(
      A1r, A1i, W1p, counts, offs, br1, bi1, mb, A2r, A2i, nullptr);
  // layer2: K=2048 split 4x512, NC=512 (NX=8) -> packed bf16 partials
  gemm_cplx<HDIM, FDIM, 8, false><<<1024, 256, 0, stream>>>(
      A2r, A2i, W2p, counts, offs, nullptr, nullptr, nullptr, nullptr, nullptr, P);

  finalize_kernel<<<TOKENS * 128 / 256, 256, 0, stream>>>(
      P, br2, bi2, perm, rexp, out);
}

// Round 10
// 129.888 us; speedup vs baseline: 1.2058x; 1.2058x over previous
//
#include <hip/hip_runtime.h>
#include <hip/hip_bf16.h>

#define TOKENS 2048
#define FDIM 512
#define HDIM 2048
#define NEXP 8
#define PI_F 3.14159265358979323846f

typedef __attribute__((ext_vector_type(8))) short bf16x8;
typedef __attribute__((ext_vector_type(4))) float f32x4;

__device__ __forceinline__ unsigned short f2bf(float f) {
  unsigned int u = __float_as_uint(f);
  unsigned int r = (u + 0x7fffu + ((u >> 16) & 1u)) >> 16;
  return (unsigned short)r;
}

__device__ __forceinline__ void gload16(const void* g, void* l) {
  __builtin_amdgcn_global_load_lds(
      (const __attribute__((address_space(1))) unsigned int*)g,
      (__attribute__((address_space(3))) unsigned int*)l, 16, 0, 0);
}

// ---------------- routing (8 tokens/block, width-32 reduce) ----------------
__global__ __launch_bounds__(256) void route_kernel(
    const float* __restrict__ xr, const float* __restrict__ xi,
    int* __restrict__ idx, int* __restrict__ counts)
{
  int tid = threadIdx.x;
  int t = blockIdx.x * 8 + (tid >> 5);
  int l = tid & 31;
  const float* r  = xr + (size_t)t * FDIM;
  const float* im = xi + (size_t)t * FDIM;
  float sc = 0.f, ss = 0.f;
  #pragma unroll
  for (int p = 0; p < 4; ++p) {
    int f = p * 128 + l * 4;
    float4 a4 = *(const float4*)(r + f);
    float4 b4 = *(const float4*)(im + f);
    float av[4] = {a4.x, a4.y, a4.z, a4.w};
    float bv[4] = {b4.x, b4.y, b4.z, b4.w};
    #pragma unroll
    for (int j = 0; j < 4; ++j) {
      float h2 = av[j] * av[j] + bv[j] * bv[j];
      if (h2 > 0.f) {
        float rs = rsqrtf(h2);
        sc += av[j] * rs;
        ss += bv[j] * rs;
      } else {
        sc += 1.f;   // atan2(0,0)=0 -> cos=1, sin=0
      }
    }
  }
  #pragma unroll
  for (int off = 16; off > 0; off >>= 1) {
    sc += __shfl_down(sc, off, 32);
    ss += __shfl_down(ss, off, 32);
  }
  if (l == 0) {
    float phase = atan2f(ss, sc);
    float norm = (phase + PI_F) / (2.f * PI_F);
    int e = (int)floorf(norm * (float)NEXP);
    e = min(max(e, 0), NEXP - 1);
    idx[t] = e;
    atomicAdd(&counts[e], 1);
  }
}

// deterministic scatter: perm within each expert in ascending token order
__global__ __launch_bounds__(256) void scatter_kernel(
    const int* __restrict__ idx, const int* __restrict__ counts,
    int* __restrict__ offs, int* __restrict__ perm, int* __restrict__ rexp)
{
  __shared__ int base_e[NEXP];
  __shared__ int tcnt[256][NEXP];
  int tid = threadIdx.x;
  if (tid == 0) {
    int acc = 0;
    for (int e = 0; e < NEXP; ++e) { base_e[e] = acc; offs[e] = acc; acc += counts[e]; }
  }
  int t0 = tid * 8;
  int eo[8];
  int loc[NEXP];
  #pragma unroll
  for (int e = 0; e < NEXP; ++e) loc[e] = 0;
  #pragma unroll
  for (int j = 0; j < 8; ++j) { eo[j] = idx[t0 + j]; loc[eo[j]]++; }
  #pragma unroll
  for (int e = 0; e < NEXP; ++e) tcnt[tid][e] = loc[e];
  __syncthreads();
  if (tid < NEXP) {
    int e = tid, run = 0;
    for (int i = 0; i < 256; ++i) { int v = tcnt[i][e]; tcnt[i][e] = run; run += v; }
  }
  __syncthreads();
  #pragma unroll
  for (int e = 0; e < NEXP; ++e) loc[e] = base_e[e] + tcnt[tid][e];
  #pragma unroll
  for (int j = 0; j < 8; ++j) {
    int e = eo[j];
    int pos = loc[e]++;
    perm[pos] = t0 + j;
    rexp[pos] = e;
  }
}

// ---------------- packing ----------------
__global__ __launch_bounds__(256) void pack_x_kernel(
    const float* __restrict__ xr, const float* __restrict__ xi,
    const int* __restrict__ perm,
    short* __restrict__ Ar, short* __restrict__ Ai)
{
  int gid = blockIdx.x * 256 + threadIdx.x;   // 2048 * 128
  int i = gid >> 7;
  int c4 = (gid & 127) * 4;
  int tok = perm[i];
  float4 r = *(const float4*)(xr + (size_t)tok * FDIM + c4);
  float4 m = *(const float4*)(xi + (size_t)tok * FDIM + c4);
  unsigned short orr[4] = { f2bf(r.x), f2bf(r.y), f2bf(r.z), f2bf(r.w) };
  unsigned short oii[4] = { f2bf(m.x), f2bf(m.y), f2bf(m.z), f2bf(m.w) };
  *(int2*)(Ar + (size_t)i * FDIM + c4) = *(const int2*)orr;
  *(int2*)(Ai + (size_t)i * FDIM + c4) = *(const int2*)oii;
}

// r5-proven: W[e][K][N] fp32 (r,i) -> Wp[e][2][N][K] bf16 (plane0=Wr^T, 1=Wi^T)
template<int K, int N>
__global__ __launch_bounds__(256) void pack_w_kernel(
    const float* __restrict__ Wr, const float* __restrict__ Wi,
    short* __restrict__ Wp)
{
  int e = blockIdx.z;
  int k0 = blockIdx.y * 32, n0 = blockIdx.x * 32;
  __shared__ float tr[32][33], ti[32][33];
  int tid = threadIdx.x;
  int row = tid >> 3, c4 = (tid & 7) * 4;
  const float* wr = Wr + ((size_t)e * K + k0) * N + n0;
  const float* wi = Wi + ((size_t)e * K + k0) * N + n0;
  float4 vr = *(const float4*)(wr + (size_t)row * N + c4);
  float4 vi = *(const float4*)(wi + (size_t)row * N + c4);
  *(float4*)&tr[row][c4] = vr;
  *(float4*)&ti[row][c4] = vi;
  __syncthreads();
  int nl = tid >> 3, k4 = (tid & 7) * 4;
  unsigned short pr[4], pi[4];
  #pragma unroll
  for (int j = 0; j < 4; ++j) {
    pr[j] = f2bf(tr[k4 + j][nl]);
    pi[j] = f2bf(ti[k4 + j][nl]);
  }
  size_t b0 = (((size_t)e * 2 + 0) * N + n0 + nl) * K + k0 + k4;
  size_t b1 = (((size_t)e * 2 + 1) * N + n0 + nl) * K + k0 + k4;
  *(int2*)(Wp + b0) = *(const int2*)pr;
  *(int2*)(Wp + b1) = *(const int2*)pi;
}

// ---------------- plane-separated complex MFMA grouped GEMM -----------------
// BM=64 x BNc=64, BK=32, 4 waves (2x2), wave-tile 32x32c (MF=2, NF=2).
// 3-deep pipeline with counted vmcnt(4) + raw s_barrier; 3 buffers of 16KB
// = 48KB total -> 3 blocks/CU resident (the r9 pipeline WITHOUT its
// occupancy loss). 256 blocks/expert (y in 0..7 covers 512 rows), expert->XCD.
template<int LDK, int NC, int NX, bool IS_L1>
__global__ __launch_bounds__(256) void gemm_cplx(
    const short* __restrict__ Apr, const short* __restrict__ Api,
    const short* __restrict__ Wp,
    const int* __restrict__ counts, const int* __restrict__ offs,
    const float* __restrict__ bre, const float* __restrict__ bim,
    const float* __restrict__ mb,
    short* __restrict__ Or, short* __restrict__ Oi,
    unsigned int* __restrict__ P)
{
  constexpr int KT = 16;                     // 16 x BK=32 = 512 K-chunk
  int bid = blockIdx.x;
  int virt = (bid & 7) * 256 + (bid >> 3);   // expert e -> XCD e
  int e = virt >> 8, rem = virt & 255;
  int x = rem % NX;
  int q = rem / NX;
  int y = q & 7, s = q >> 3;                 // IS_L1: s=0
  int cnt = counts[e];
  int row0 = y * 64;
  if (row0 >= cnt) return;
  int base = offs[e];
  int n0c = x * 64;
  int kbase = s * 512;

  __shared__ __align__(16) short As[3][2][64][32];   // 24KB [buf][plane][row][k]
  __shared__ __align__(16) short Ws[3][2][64][32];   // 24KB

  int tid = threadIdx.x;
  int lane = tid & 63;
  int w = tid >> 6, wm = w >> 1, wn = w & 1;
  int lr = lane & 15, g = lane >> 4;
  int ssw = g ^ ((lr >> 1) & 3);             // swizzled 16B slot for reads

  int srl = tid >> 2, slt = tid & 3;
  int sc = (slt ^ ((srl >> 1) & 3)) * 16;    // pre-swizzled source byte offset
  int arow = min(row0 + srl, cnt - 1);
  const char* pAr = (const char*)(Apr + (size_t)(base + arow) * LDK + kbase) + sc;
  const char* pAi = (const char*)(Api + (size_t)(base + arow) * LDK + kbase) + sc;
  const short* We = Wp + (size_t)e * 2 * NC * LDK;
  const char* pW0 = (const char*)(We + (size_t)(n0c + srl) * LDK + kbase) + sc;
  const char* pW1 = (const char*)(We + ((size_t)NC + n0c + srl) * LDK + kbase) + sc;

  auto STAGE = [&](int buf, int t) {         // 4 gload16 per thread
    char* ab = (char*)&As[0][0][0][0] + buf * 8192;
    gload16(pAr + t * 64, ab + tid * 16);
    gload16(pAi + t * 64, ab + 4096 + tid * 16);
    char* wb = (char*)&Ws[0][0][0][0] + buf * 8192;
    gload16(pW0 + t * 64, wb + tid * 16);
    gload16(pW1 + t * 64, wb + 4096 + tid * 16);
  };

  f32x4 accr[2][2], acci[2][2];
  #pragma unroll
  for (int m = 0; m < 2; ++m)
    #pragma unroll
    for (int n = 0; n < 2; ++n) { accr[m][n] = 0.f; acci[m][n] = 0.f; }

  const bf16x8 SGN = {(short)0x8000, (short)0x8000, (short)0x8000, (short)0x8000,
                      (short)0x8000, (short)0x8000, (short)0x8000, (short)0x8000};

  auto COMPUTE = [&](int buf) {
    const short* Ab = &As[0][0][0][0] + buf * 4096;
    const short* Wb = &Ws[0][0][0][0] + buf * 4096;
    bf16x8 ar[2], ai[2], wr[2], wi[2], wni[2];
    #pragma unroll
    for (int m = 0; m < 2; ++m) {
      int off = (wm * 32 + m * 16 + lr) * 32 + ssw * 8;
      ar[m] = *(const bf16x8*)(Ab + off);
      ai[m] = *(const bf16x8*)(Ab + 2048 + off);
    }
    #pragma unroll
    for (int n = 0; n < 2; ++n) {
      int offw = (wn * 32 + n * 16 + lr) * 32 + ssw * 8;
      wr[n] = *(const bf16x8*)(Wb + offw);
      wi[n] = *(const bf16x8*)(Wb + 2048 + offw);
      wni[n] = wi[n] ^ SGN;
    }
    #pragma unroll
    for (int m = 0; m < 2; ++m)
      #pragma unroll
      for (int n = 0; n < 2; ++n) {
        accr[m][n] = __builtin_amdgcn_mfma_f32_16x16x32_bf16(ar[m], wr[n],  accr[m][n], 0, 0, 0);
        accr[m][n] = __builtin_amdgcn_mfma_f32_16x16x32_bf16(ai[m], wni[n], accr[m][n], 0, 0, 0);
        acci[m][n] = __builtin_amdgcn_mfma_f32_16x16x32_bf16(ar[m], wi[n],  acci[m][n], 0, 0, 0);
        acci[m][n] = __builtin_amdgcn_mfma_f32_16x16x32_bf16(ai[m], wr[n],  acci[m][n], 0, 0, 0);
      }
  };

  STAGE(0, 0);
  STAGE(1, 1);
  for (int t = 0; t < KT; ++t) {
    // wait for tile t's 4 loads only; tile t+1's 4 remain in flight (T4)
    if (t < KT - 1) asm volatile("s_waitcnt vmcnt(4)" ::: "memory");
    else            asm volatile("s_waitcnt vmcnt(0)" ::: "memory");
    __builtin_amdgcn_s_barrier();
    if (t + 2 < KT) STAGE((t + 2) % 3, t + 2);
    COMPUTE(t % 3);
  }

  // epilogue (no LDS use -> no trailing barrier needed)
  #pragma unroll
  for (int m = 0; m < 2; ++m) {
    #pragma unroll
    for (int qq = 0; qq < 4; ++qq) {
      int row = row0 + wm * 32 + m * 16 + g * 4 + qq;
      if (row >= cnt) continue;
      #pragma unroll
      for (int n = 0; n < 2; ++n) {
        int c = n0c + wn * 32 + n * 16 + lr;
        if constexpr (IS_L1) {
          float hr = accr[m][n][qq] + bre[e * NC + c];
          float hi = acci[m][n][qq] + bim[e * NC + c];
          float s2 = hr * hr + hi * hi + 1e-10f;
          float rr = __frsqrt_rn(s2);
          float amp = s2 * rr;
          float scl = fmaxf(amp + mb[e * NC + c], 0.f) * rr;
          Or[(size_t)(base + row) * NC + c] = (short)f2bf(hr * scl);
          Oi[(size_t)(base + row) * NC + c] = (short)f2bf(hi * scl);
        } else {
          // packed bf16 partial: lo16 = re, hi16 = im
          unsigned pv = (unsigned)f2bf(accr[m][n][qq])
                      | ((unsigned)f2bf(acci[m][n][qq]) << 16);
          P[((size_t)s * TOKENS + base + row) * 512 + c] = pv;
        }
      }
    }
  }
}

// ---------------- split-K finalize (bf16 packed partials) ----------------
__global__ __launch_bounds__(256) void finalize_kernel(
    const unsigned int* __restrict__ P, const float* __restrict__ br2,
    const float* __restrict__ bi2, const int* __restrict__ perm,
    const int* __restrict__ rexp, float* __restrict__ out)
{
  int gid = blockIdx.x * 256 + threadIdx.x;   // 2048 * 128
  int i = gid >> 7;
  int c4 = (gid & 127) * 4;
  float sr[4] = {0.f, 0.f, 0.f, 0.f}, si[4] = {0.f, 0.f, 0.f, 0.f};
  #pragma unroll
  for (int s = 0; s < 4; ++s) {
    uint4 u = *(const uint4*)(P + ((size_t)s * TOKENS + i) * 512 + c4);
    unsigned uv[4] = {u.x, u.y, u.z, u.w};
    #pragma unroll
    for (int j = 0; j < 4; ++j) {
      sr[j] += __uint_as_float(uv[j] << 16);
      si[j] += __uint_as_float(uv[j] & 0xFFFF0000u);
    }
  }
  int e = rexp[i], tok = perm[i];
  float4 br = *(const float4*)(br2 + e * FDIM + c4);
  float4 bi = *(const float4*)(bi2 + e * FDIM + c4);
  float4 vr = {sr[0] + br.x, sr[1] + br.y, sr[2] + br.z, sr[3] + br.w};
  float4 vi = {si[0] + bi.x, si[1] + bi.y, si[2] + bi.z, si[3] + bi.w};
  *(float4*)(out + (size_t)tok * FDIM + c4) = vr;
  *(float4*)(out + (size_t)TOKENS * FDIM + (size_t)tok * FDIM + c4) = vi;
}

extern "C" void kernel_launch(void* const* d_in, const int* in_sizes, int n_in,
                              void* d_out, int out_size, void* d_ws, size_t ws_size,
                              hipStream_t stream)
{
  const float* xr  = (const float*)d_in[0];
  const float* xi  = (const float*)d_in[1];
  const float* Wr1 = (const float*)d_in[2];
  const float* Wi1 = (const float*)d_in[3];
  const float* br1 = (const float*)d_in[4];
  const float* bi1 = (const float*)d_in[5];
  const float* mb  = (const float*)d_in[6];
  const float* Wr2 = (const float*)d_in[7];
  const float* Wi2 = (const float*)d_in[8];
  const float* br2 = (const float*)d_in[9];
  const float* bi2 = (const float*)d_in[10];
  float* out = (float*)d_out;

  char* ws = (char*)d_ws;
  int* counts = (int*)(ws + 0);
  int* offs   = (int*)(ws + 64);
  int* idx    = (int*)(ws + 128);
  int* perm   = (int*)(ws + 8320);
  int* rexp   = (int*)(ws + 16512);

  size_t off = 32768;
  short* A1r = (short*)(ws + off); off += (size_t)TOKENS * FDIM * 2;
  short* A1i = (short*)(ws + off); off += (size_t)TOKENS * FDIM * 2;
  short* A2r = (short*)(ws + off); off += (size_t)TOKENS * HDIM * 2;
  short* A2i = (short*)(ws + off); off += (size_t)TOKENS * HDIM * 2;
  short* W1p = (short*)(ws + off); off += (size_t)NEXP * 2 * HDIM * FDIM * 2;
  short* W2p = (short*)(ws + off); off += (size_t)NEXP * 2 * FDIM * HDIM * 2;
  unsigned int* P = (unsigned int*)(ws + off);   // 4 x 2048 x 512 uints = 16MB

  hipMemsetAsync(counts, 0, 64, stream);
  route_kernel<<<TOKENS / 8, 256, 0, stream>>>(xr, xi, idx, counts);
  scatter_kernel<<<1, 256, 0, stream>>>(idx, counts, offs, perm, rexp);

  pack_x_kernel<<<TOKENS * 128 / 256, 256, 0, stream>>>(xr, xi, perm, A1r, A1i);
  pack_w_kernel<FDIM, HDIM><<<dim3(HDIM / 32, FDIM / 32, NEXP), 256, 0, stream>>>(
      Wr1, Wi1, W1p);
  pack_w_kernel<HDIM, FDIM><<<dim3(FDIM / 32, HDIM / 32, NEXP), 256, 0, stream>>>(
      Wr2, Wi2, W2p);

  // layer1: K=512, NC=2048 (NX=32) -> A2 planes (bias+ModReLU fused)
  gemm_cplx<FDIM, HDIM, 32, true><<<2048, 256, 0, stream>>>(
      A1r, A1i, W1p, counts, offs, br1, bi1, mb, A2r, A2i, nullptr);
  // layer2: K=2048 split 4x512, NC=512 (NX=8) -> packed bf16 partials
  gemm_cplx<HDIM, FDIM, 8, false><<<2048, 256, 0, stream>>>(
      A2r, A2i, W2p, counts, offs, nullptr, nullptr, nullptr, nullptr, nullptr, P);

  finalize_kernel<<<TOKENS * 128 / 256, 256, 0, stream>>>(
      P, br2, bi2, perm, rexp, out);
}

// Round 11
// 123.095 us; speedup vs baseline: 1.2723x; 1.0552x over previous
//
#include <hip/hip_runtime.h>
#include <hip/hip_bf16.h>

#define TOKENS 2048
#define FDIM 512
#define HDIM 2048
#define NEXP 8
#define PI_F 3.14159265358979323846f

typedef __attribute__((ext_vector_type(8))) short bf16x8;
typedef __attribute__((ext_vector_type(4))) float f32x4;

__device__ __forceinline__ unsigned short f2bf(float f) {
  unsigned int u = __float_as_uint(f);
  unsigned int r = (u + 0x7fffu + ((u >> 16) & 1u)) >> 16;
  return (unsigned short)r;
}

__device__ __forceinline__ void gload16(const void* g, void* l) {
  __builtin_amdgcn_global_load_lds(
      (const __attribute__((address_space(1))) unsigned int*)g,
      (__attribute__((address_space(3))) unsigned int*)l, 16, 0, 0);
}

// ---------- fused route (256 blocks) + pack_w (2x8192 blocks) ----------
// pack body (r5-proven): W[e][K][N] fp32 -> Wp[e][2][N][K] bf16
template<int K, int N>
__device__ __forceinline__ void pack_w_body(
    const float* __restrict__ Wr, const float* __restrict__ Wi,
    short* __restrict__ Wp, int b, float (*tr)[33], float (*ti)[33])
{
  int per_e = (K / 32) * (N / 32);
  int e = b / per_e;
  int rem = b % per_e;
  int k0 = (rem / (N / 32)) * 32, n0 = (rem % (N / 32)) * 32;
  int tid = threadIdx.x;
  int row = tid >> 3, c4 = (tid & 7) * 4;
  const float* wr = Wr + ((size_t)e * K + k0) * N + n0;
  const float* wi = Wi + ((size_t)e * K + k0) * N + n0;
  float4 vr = *(const float4*)(wr + (size_t)row * N + c4);
  float4 vi = *(const float4*)(wi + (size_t)row * N + c4);
  *(float4*)&tr[row][c4] = vr;
  *(float4*)&ti[row][c4] = vi;
  __syncthreads();
  int nl = tid >> 3, k4 = (tid & 7) * 4;
  unsigned short pr[4], pi[4];
  #pragma unroll
  for (int j = 0; j < 4; ++j) {
    pr[j] = f2bf(tr[k4 + j][nl]);
    pi[j] = f2bf(ti[k4 + j][nl]);
  }
  size_t b0 = (((size_t)e * 2 + 0) * N + n0 + nl) * K + k0 + k4;
  size_t b1 = (((size_t)e * 2 + 1) * N + n0 + nl) * K + k0 + k4;
  *(int2*)(Wp + b0) = *(const int2*)pr;
  *(int2*)(Wp + b1) = *(const int2*)pi;
}

__global__ __launch_bounds__(256) void route_packw_kernel(
    const float* __restrict__ xr, const float* __restrict__ xi,
    int* __restrict__ idx, int* __restrict__ counts,
    const float* __restrict__ Wr1, const float* __restrict__ Wi1,
    const float* __restrict__ Wr2, const float* __restrict__ Wi2,
    short* __restrict__ W1p, short* __restrict__ W2p)
{
  __shared__ float tr[32][33], ti[32][33];
  int bid = blockIdx.x;
  if (bid < 256) {
    // route: 8 tokens per block, width-32 reduce (r7-proven)
    int tid = threadIdx.x;
    int t = bid * 8 + (tid >> 5);
    int l = tid & 31;
    const float* r  = xr + (size_t)t * FDIM;
    const float* im = xi + (size_t)t * FDIM;
    float sc = 0.f, ss = 0.f;
    #pragma unroll
    for (int p = 0; p < 4; ++p) {
      int f = p * 128 + l * 4;
      float4 a4 = *(const float4*)(r + f);
      float4 b4 = *(const float4*)(im + f);
      float av[4] = {a4.x, a4.y, a4.z, a4.w};
      float bv[4] = {b4.x, b4.y, b4.z, b4.w};
      #pragma unroll
      for (int j = 0; j < 4; ++j) {
        float h2 = av[j] * av[j] + bv[j] * bv[j];
        if (h2 > 0.f) {
          float rs = rsqrtf(h2);
          sc += av[j] * rs;
          ss += bv[j] * rs;
        } else {
          sc += 1.f;   // atan2(0,0)=0 -> cos=1, sin=0
        }
      }
    }
    #pragma unroll
    for (int off = 16; off > 0; off >>= 1) {
      sc += __shfl_down(sc, off, 32);
      ss += __shfl_down(ss, off, 32);
    }
    if (l == 0) {
      float phase = atan2f(ss, sc);
      float norm = (phase + PI_F) / (2.f * PI_F);
      int e = (int)floorf(norm * (float)NEXP);
      e = min(max(e, 0), NEXP - 1);
      idx[t] = e;
      atomicAdd(&counts[e], 1);
    }
  } else {
    int b = bid - 256;
    if (b < 8192) pack_w_body<FDIM, HDIM>(Wr1, Wi1, W1p, b, tr, ti);
    else          pack_w_body<HDIM, FDIM>(Wr2, Wi2, W2p, b - 8192, tr, ti);
  }
}

// deterministic scatter: perm within each expert in ascending token order
__global__ __launch_bounds__(256) void scatter_kernel(
    const int* __restrict__ idx, const int* __restrict__ counts,
    int* __restrict__ offs, int* __restrict__ perm, int* __restrict__ rexp)
{
  __shared__ int base_e[NEXP];
  __shared__ int tcnt[256][NEXP];
  int tid = threadIdx.x;
  if (tid == 0) {
    int acc = 0;
    for (int e = 0; e < NEXP; ++e) { base_e[e] = acc; offs[e] = acc; acc += counts[e]; }
  }
  int t0 = tid * 8;
  int eo[8];
  int loc[NEXP];
  #pragma unroll
  for (int e = 0; e < NEXP; ++e) loc[e] = 0;
  #pragma unroll
  for (int j = 0; j < 8; ++j) { eo[j] = idx[t0 + j]; loc[eo[j]]++; }
  #pragma unroll
  for (int e = 0; e < NEXP; ++e) tcnt[tid][e] = loc[e];
  __syncthreads();
  if (tid < NEXP) {
    int e = tid, run = 0;
    for (int i = 0; i < 256; ++i) { int v = tcnt[i][e]; tcnt[i][e] = run; run += v; }
  }
  __syncthreads();
  #pragma unroll
  for (int e = 0; e < NEXP; ++e) loc[e] = base_e[e] + tcnt[tid][e];
  #pragma unroll
  for (int j = 0; j < 8; ++j) {
    int e = eo[j];
    int pos = loc[e]++;
    perm[pos] = t0 + j;
    rexp[pos] = e;
  }
}

// ---------------- packing x ----------------
__global__ __launch_bounds__(256) void pack_x_kernel(
    const float* __restrict__ xr, const float* __restrict__ xi,
    const int* __restrict__ perm,
    short* __restrict__ Ar, short* __restrict__ Ai)
{
  int gid = blockIdx.x * 256 + threadIdx.x;   // 2048 * 128
  int i = gid >> 7;
  int c4 = (gid & 127) * 4;
  int tok = perm[i];
  float4 r = *(const float4*)(xr + (size_t)tok * FDIM + c4);
  float4 m = *(const float4*)(xi + (size_t)tok * FDIM + c4);
  unsigned short orr[4] = { f2bf(r.x), f2bf(r.y), f2bf(r.z), f2bf(r.w) };
  unsigned short oii[4] = { f2bf(m.x), f2bf(m.y), f2bf(m.z), f2bf(m.w) };
  *(int2*)(Ar + (size_t)i * FDIM + c4) = *(const int2*)orr;
  *(int2*)(Ai + (size_t)i * FDIM + c4) = *(const int2*)oii;
}

// ---------------- plane-separated complex MFMA grouped GEMM -----------------
// BM=64 x BNc=64, BK=32, 4 waves (2x2), wave-tile 32x32c (MF=2, NF=2).
// 2-buffer pipeline, 32KB LDS -> all 4 dispatched blocks/CU resident.
// Counted vmcnt(4): tile t+1's loads stay in flight across the barrier.
// WAR on buffer reuse (distance 2) protected by barrier after COMPUTE.
template<int LDK, int NC, int NX, bool IS_L1>
__global__ __launch_bounds__(256) void gemm_cplx(
    const short* __restrict__ Apr, const short* __restrict__ Api,
    const short* __restrict__ Wp,
    const int* __restrict__ counts, const int* __restrict__ offs,
    const float* __restrict__ bre, const float* __restrict__ bim,
    const float* __restrict__ mb,
    short* __restrict__ Or, short* __restrict__ Oi,
    unsigned int* __restrict__ P)
{
  constexpr int KT = 16;                     // 16 x BK=32 = 512 K-chunk
  int bid = blockIdx.x;
  int virt = (bid & 7) * 256 + (bid >> 3);   // expert e -> XCD e
  int e = virt >> 8, rem = virt & 255;
  int x = rem % NX;
  int q = rem / NX;
  int y = q & 7, s = q >> 3;                 // IS_L1: s=0
  int cnt = counts[e];
  int row0 = y * 64;
  if (row0 >= cnt) return;
  int base = offs[e];
  int n0c = x * 64;
  int kbase = s * 512;

  __shared__ __align__(16) short As[2][2][64][32];   // 16KB [buf][plane][row][k]
  __shared__ __align__(16) short Ws[2][2][64][32];   // 16KB

  int tid = threadIdx.x;
  int lane = tid & 63;
  int w = tid >> 6, wm = w >> 1, wn = w & 1;
  int lr = lane & 15, g = lane >> 4;
  int ssw = g ^ ((lr >> 1) & 3);             // swizzled 16B slot for reads

  int srl = tid >> 2, slt = tid & 3;
  int sc = (slt ^ ((srl >> 1) & 3)) * 16;    // pre-swizzled source byte offset
  int arow = min(row0 + srl, cnt - 1);
  const char* pAr = (const char*)(Apr + (size_t)(base + arow) * LDK + kbase) + sc;
  const char* pAi = (const char*)(Api + (size_t)(base + arow) * LDK + kbase) + sc;
  const short* We = Wp + (size_t)e * 2 * NC * LDK;
  const char* pW0 = (const char*)(We + (size_t)(n0c + srl) * LDK + kbase) + sc;
  const char* pW1 = (const char*)(We + ((size_t)NC + n0c + srl) * LDK + kbase) + sc;

  auto STAGE = [&](int buf, int t) {         // 4 gload16 per thread
    char* ab = (char*)&As[0][0][0][0] + buf * 8192;
    gload16(pAr + t * 64, ab + tid * 16);
    gload16(pAi + t * 64, ab + 4096 + tid * 16);
    char* wb = (char*)&Ws[0][0][0][0] + buf * 8192;
    gload16(pW0 + t * 64, wb + tid * 16);
    gload16(pW1 + t * 64, wb + 4096 + tid * 16);
  };

  f32x4 accr[2][2], acci[2][2];
  #pragma unroll
  for (int m = 0; m < 2; ++m)
    #pragma unroll
    for (int n = 0; n < 2; ++n) { accr[m][n] = 0.f; acci[m][n] = 0.f; }

  const bf16x8 SGN = {(short)0x8000, (short)0x8000, (short)0x8000, (short)0x8000,
                      (short)0x8000, (short)0x8000, (short)0x8000, (short)0x8000};

  auto COMPUTE = [&](int buf) {
    const short* Ab = &As[0][0][0][0] + buf * 4096;
    const short* Wb = &Ws[0][0][0][0] + buf * 4096;
    bf16x8 ar[2], ai[2], wr[2], wi[2], wni[2];
    #pragma unroll
    for (int m = 0; m < 2; ++m) {
      int off = (wm * 32 + m * 16 + lr) * 32 + ssw * 8;
      ar[m] = *(const bf16x8*)(Ab + off);
      ai[m] = *(const bf16x8*)(Ab + 2048 + off);
    }
    #pragma unroll
    for (int n = 0; n < 2; ++n) {
      int offw = (wn * 32 + n * 16 + lr) * 32 + ssw * 8;
      wr[n] = *(const bf16x8*)(Wb + offw);
      wi[n] = *(const bf16x8*)(Wb + 2048 + offw);
      wni[n] = wi[n] ^ SGN;
    }
    #pragma unroll
    for (int m = 0; m < 2; ++m)
      #pragma unroll
      for (int n = 0; n < 2; ++n) {
        accr[m][n] = __builtin_amdgcn_mfma_f32_16x16x32_bf16(ar[m], wr[n],  accr[m][n], 0, 0, 0);
        accr[m][n] = __builtin_amdgcn_mfma_f32_16x16x32_bf16(ai[m], wni[n], accr[m][n], 0, 0, 0);
        acci[m][n] = __builtin_amdgcn_mfma_f32_16x16x32_bf16(ar[m], wi[n],  acci[m][n], 0, 0, 0);
        acci[m][n] = __builtin_amdgcn_mfma_f32_16x16x32_bf16(ai[m], wr[n],  acci[m][n], 0, 0, 0);
      }
  };

  STAGE(0, 0);
  STAGE(1, 1);
  for (int t = 0; t < KT; ++t) {
    // wait tile t's 4 loads; tile t+1's 4 remain in flight across barrier (T4)
    if (t < KT - 1) asm volatile("s_waitcnt vmcnt(4)" ::: "memory");
    else            asm volatile("s_waitcnt vmcnt(0)" ::: "memory");
    __builtin_amdgcn_s_barrier();
    COMPUTE(t & 1);
    __builtin_amdgcn_s_barrier();              // all reads of buf (t&1) done
    if (t + 2 < KT) STAGE(t & 1, t + 2);       // safe overwrite (WAR fenced)
  }

  // epilogue
  #pragma unroll
  for (int m = 0; m < 2; ++m) {
    #pragma unroll
    for (int qq = 0; qq < 4; ++qq) {
      int row = row0 + wm * 32 + m * 16 + g * 4 + qq;
      if (row >= cnt) continue;
      #pragma unroll
      for (int n = 0; n < 2; ++n) {
        int c = n0c + wn * 32 + n * 16 + lr;
        if constexpr (IS_L1) {
          float hr = accr[m][n][qq] + bre[e * NC + c];
          float hi = acci[m][n][qq] + bim[e * NC + c];
          float s2 = hr * hr + hi * hi + 1e-10f;
          float rr = __frsqrt_rn(s2);
          float amp = s2 * rr;
          float scl = fmaxf(amp + mb[e * NC + c], 0.f) * rr;
          Or[(size_t)(base + row) * NC + c] = (short)f2bf(hr * scl);
          Oi[(size_t)(base + row) * NC + c] = (short)f2bf(hi * scl);
        } else {
          // packed bf16 partial: lo16 = re, hi16 = im
          unsigned pv = (unsigned)f2bf(accr[m][n][qq])
                      | ((unsigned)f2bf(acci[m][n][qq]) << 16);
          P[((size_t)s * TOKENS + base + row) * 512 + c] = pv;
        }
      }
    }
  }
}

// ---------------- split-K finalize (bf16 packed partials) ----------------
__global__ __launch_bounds__(256) void finalize_kernel(
    const unsigned int* __restrict__ P, const float* __restrict__ br2,
    const float* __restrict__ bi2, const int* __restrict__ perm,
    const int* __restrict__ rexp, float* __restrict__ out)
{
  int gid = blockIdx.x * 256 + threadIdx.x;   // 2048 * 128
  int i = gid >> 7;
  int c4 = (gid & 127) * 4;
  float sr[4] = {0.f, 0.f, 0.f, 0.f}, si[4] = {0.f, 0.f, 0.f, 0.f};
  #pragma unroll
  for (int s = 0; s < 4; ++s) {
    uint4 u = *(const uint4*)(P + ((size_t)s * TOKENS + i) * 512 + c4);
    unsigned uv[4] = {u.x, u.y, u.z, u.w};
    #pragma unroll
    for (int j = 0; j < 4; ++j) {
      sr[j] += __uint_as_float(uv[j] << 16);
      si[j] += __uint_as_float(uv[j] & 0xFFFF0000u);
    }
  }
  int e = rexp[i], tok = perm[i];
  float4 br = *(const float4*)(br2 + e * FDIM + c4);
  float4 bi = *(const float4*)(bi2 + e * FDIM + c4);
  float4 vr = {sr[0] + br.x, sr[1] + br.y, sr[2] + br.z, sr[3] + br.w};
  float4 vi = {si[0] + bi.x, si[1] + bi.y, si[2] + bi.z, si[3] + bi.w};
  *(float4*)(out + (size_t)tok * FDIM + c4) = vr;
  *(float4*)(out + (size_t)TOKENS * FDIM + (size_t)tok * FDIM + c4) = vi;
}

extern "C" void kernel_launch(void* const* d_in, const int* in_sizes, int n_in,
                              void* d_out, int out_size, void* d_ws, size_t ws_size,
                              hipStream_t stream)
{
  const float* xr  = (const float*)d_in[0];
  const float* xi  = (const float*)d_in[1];
  const float* Wr1 = (const float*)d_in[2];
  const float* Wi1 = (const float*)d_in[3];
  const float* br1 = (const float*)d_in[4];
  const float* bi1 = (const float*)d_in[5];
  const float* mb  = (const float*)d_in[6];
  const float* Wr2 = (const float*)d_in[7];
  const float* Wi2 = (const float*)d_in[8];
  const float* br2 = (const float*)d_in[9];
  const float* bi2 = (const float*)d_in[10];
  float* out = (float*)d_out;

  char* ws = (char*)d_ws;
  int* counts = (int*)(ws + 0);
  int* offs   = (int*)(ws + 64);
  int* idx    = (int*)(ws + 128);
  int* perm   = (int*)(ws + 8320);
  int* rexp   = (int*)(ws + 16512);

  size_t off = 32768;
  short* A1r = (short*)(ws + off); off += (size_t)TOKENS * FDIM * 2;
  short* A1i = (short*)(ws + off); off += (size_t)TOKENS * FDIM * 2;
  short* A2r = (short*)(ws + off); off += (size_t)TOKENS * HDIM * 2;
  short* A2i = (short*)(ws + off); off += (size_t)TOKENS * HDIM * 2;
  short* W1p = (short*)(ws + off); off += (size_t)NEXP * 2 * HDIM * FDIM * 2;
  short* W2p = (short*)(ws + off); off += (size_t)NEXP * 2 * FDIM * HDIM * 2;
  unsigned int* P = (unsigned int*)(ws + off);   // 4 x 2048 x 512 uints = 16MB

  hipMemsetAsync(counts, 0, 64, stream);
  // route (256 blocks) runs concurrently with both weight packs (16384 blocks)
  route_packw_kernel<<<256 + 16384, 256, 0, stream>>>(
      xr, xi, idx, counts, Wr1, Wi1, Wr2, Wi2, W1p, W2p);
  scatter_kernel<<<1, 256, 0, stream>>>(idx, counts, offs, perm, rexp);
  pack_x_kernel<<<TOKENS * 128 / 256, 256, 0, stream>>>(xr, xi, perm, A1r, A1i);

  // layer1: K=512, NC=2048 (NX=32) -> A2 planes (bias+ModReLU fused)
  gemm_cplx<FDIM, HDIM, 32, true><<<2048, 256, 0, stream>>>(
      A1r, A1i, W1p, counts, offs, br1, bi1, mb, A2r, A2i, nullptr);
  // layer2: K=2048 split 4x512, NC=512 (NX=8) -> packed bf16 partials
  gemm_cplx<HDIM, FDIM, 8, false><<<2048, 256, 0, stream>>>(
      A2r, A2i, W2p, counts, offs, nullptr, nullptr, nullptr, nullptr, nullptr, P);

  finalize_kernel<<<TOKENS * 128 / 256, 256, 0, stream>>>(
      P, br2, bi2, perm, rexp, out);
}